// Round 9
// baseline (411.111 us; speedup 1.0000x reference)
//
#include <hip/hip_runtime.h>
#include <hip/hip_bf16.h>
#include <math.h>

#define D_MODEL 1024
#define D_STATE 16
#define D_CONV 4
#define D_INNER 2048
#define DT_RANK 64
#define BATCH 2
#define SEQ 2048
#define NTOK (BATCH*SEQ)   // 4096
#define EPS 1e-5f
#define CCH 32             // scan chunks per sequence
#define TCH (SEQ/CCH)      // 64 tokens per chunk
#define XKS 8              // x_proj split-K factor
#define XKC (D_INNER/XKS)  // 256 K per chunk

typedef __attribute__((ext_vector_type(8))) short short8;
typedef __attribute__((ext_vector_type(4))) float f32x4;
typedef __attribute__((ext_vector_type(4))) unsigned short us4;

__device__ inline unsigned short f2bf(float f) {
  union { __hip_bfloat16 h; unsigned short u; } c;
  c.h = __float2bfloat16(f);
  return c.u;
}
__device__ inline float bf2f(unsigned short u) {
  union { unsigned int i; float f; } c;
  c.i = ((unsigned int)u) << 16;
  return c.f;
}

#define GLL(gp, lp) __builtin_amdgcn_global_load_lds( \
    (const __attribute__((address_space(1))) void*)(gp), \
    (__attribute__((address_space(3))) void*)(lp), 16, 0, 0)

// ---------------- fused fp32 -> bf16 convert for the 4 weight tensors ----------------
__global__ __launch_bounds__(256) void f2bf4_kernel(
    const float* __restrict__ i0, unsigned short* __restrict__ o0, int b0,
    const float* __restrict__ i1, unsigned short* __restrict__ o1, int b1,
    const float* __restrict__ i2, unsigned short* __restrict__ o2, int b2,
    const float* __restrict__ i3, unsigned short* __restrict__ o3)
{
  int blk = blockIdx.x;
  const float* in; unsigned short* out; int base;
  if (blk < b0)           { in = i0; out = o0; base = blk; }
  else if (blk < b0+b1)   { in = i1; out = o1; base = blk - b0; }
  else if (blk < b0+b1+b2){ in = i2; out = o2; base = blk - b0 - b1; }
  else                    { in = i3; out = o3; base = blk - b0 - b1 - b2; }
  int i = (base*256 + threadIdx.x)*4;
  float4 v = *(const float4*)(in + i);
  us4 o;
  o[0] = f2bf(v.x); o[1] = f2bf(v.y); o[2] = f2bf(v.z); o[3] = f2bf(v.w);
  *(us4*)(out + i) = o;
}

// ---------------- RMSNorm: one block per token, bf16 output ----------------
__global__ __launch_bounds__(256) void rmsnorm_kernel(const float* __restrict__ x,
                                                      const float* __restrict__ w,
                                                      unsigned short* __restrict__ xn) {
  int tok = blockIdx.x;
  const float* xr = x + (size_t)tok * D_MODEL;
  unsigned short* xo = xn + (size_t)tok * D_MODEL;
  int t = threadIdx.x;
  float4 v = ((const float4*)xr)[t];
  float ss = v.x*v.x + v.y*v.y + v.z*v.z + v.w*v.w;
  #pragma unroll
  for (int off = 32; off > 0; off >>= 1) ss += __shfl_down(ss, off, 64);
  __shared__ float wsum[4];
  __shared__ float rinv_s;
  int lane = t & 63, wv = t >> 6;
  if (lane == 0) wsum[wv] = ss;
  __syncthreads();
  if (t == 0) {
    float tot = wsum[0] + wsum[1] + wsum[2] + wsum[3];
    rinv_s = 1.0f / sqrtf(tot / (float)D_MODEL + EPS);
  }
  __syncthreads();
  float rinv = rinv_s;
  float4 g = ((const float4*)w)[t];
  us4 o;
  o[0] = f2bf(v.x * rinv * g.x);
  o[1] = f2bf(v.y * rinv * g.y);
  o[2] = f2bf(v.z * rinv * g.z);
  o[3] = f2bf(v.w * rinv * g.w);
  *(us4*)(xo + t*4) = o;
}

// ================== 256x256 8-phase bf16 MFMA GEMM (in_proj) ==================
// (unchanged from R7 — verified working; see R7 notes)
template<int NT>   // K = NT*64
__global__ __launch_bounds__(512) void gemm256_bf16_kernel(
    const unsigned short* __restrict__ A,   // [M][K]
    const unsigned short* __restrict__ W,   // [N][K]
    unsigned short* __restrict__ C, int ldc)
{
  const int K = NT*64;
  __shared__ __align__(16) unsigned short As[2][16384];
  __shared__ __align__(16) unsigned short Bs[2][16384];
  int tid = threadIdx.x;
  int lane = tid & 63;
  int w = tid >> 6;          // 0..7
  int wm = w >> 2, wn = w & 3;
  int bm = blockIdx.x * 256;
  int bn = blockIdx.y * 256;
  int r15 = lane & 15, g8 = (lane >> 4) * 8;
  int rbh0 = (w & 3) + (w >> 2) * 8;   // this wave's ih0 staging row-block
  int rbh1 = rbh0 + 4;                 // ih1 staging row-block

  auto stageA = [&](int slot, int tile, int ks, int rb) {
    const unsigned short* src = A + (size_t)(bm + rb*16 + r15) * K + tile*64 + ks*32 + g8;
    GLL(src, &As[slot][rb*1024 + ks*512]);
  };
  auto stageB = [&](int slot, int tile, int ks, int cb) {
    const unsigned short* src = W + (size_t)(bn + cb*16 + r15) * K + tile*64 + ks*32 + g8;
    GLL(src, &Bs[slot][cb*1024 + ks*512]);
  };

  stageA(0,0,0,rbh0); stageB(0,0,0,w); stageB(0,0,0,8+w);
  stageA(0,0,0,rbh1);
  stageA(0,0,1,rbh0); stageB(0,0,1,w); stageB(0,0,1,8+w);
  stageA(0,0,1,rbh1);
  stageA(1,1,0,rbh0); stageB(1,1,0,w); stageB(1,1,0,8+w);
  stageA(1,1,0,rbh1);
  stageA(1,1,1,rbh0); stageB(1,1,1,w); stageB(1,1,1,8+w);
  asm volatile("s_waitcnt vmcnt(7)" ::: "memory");   // tile0 resident
  __builtin_amdgcn_s_barrier();
  __builtin_amdgcn_sched_barrier(0);

  f32x4 acc[8][4] = {};
  short8 bfr[4];

#define PHASE_END()                                                      \
  if (drain) { asm volatile("s_waitcnt vmcnt(0)" ::: "memory"); }        \
  else       { asm volatile("s_waitcnt vmcnt(12)" ::: "memory"); }       \
  __builtin_amdgcn_s_barrier();                                          \
  __builtin_amdgcn_sched_barrier(0);

#define MFMA16(IH)                                                       \
  __builtin_amdgcn_s_setprio(1);                                         \
  _Pragma("unroll")                                                      \
  for (int ii = 0; ii < 4; ++ii) {                                       \
    _Pragma("unroll")                                                    \
    for (int j = 0; j < 4; ++j)                                          \
      acc[(IH)*4+ii][j] = __builtin_amdgcn_mfma_f32_16x16x32_bf16(       \
          af[ii], bfr[j], acc[(IH)*4+ii][j], 0, 0, 0);                   \
  }                                                                      \
  __builtin_amdgcn_s_setprio(0);

#define LOAD_A(KS, IH)                                                   \
  short8 af[4];                                                          \
  _Pragma("unroll")                                                      \
  for (int ii = 0; ii < 4; ++ii)                                         \
    af[ii] = *(const short8*)&As[s][(wm*8 + (IH)*4 + ii)*1024 + (KS)*512 + lane*8];

#define LOAD_B(KS)                                                       \
  _Pragma("unroll")                                                      \
  for (int j = 0; j < 4; ++j)                                            \
    bfr[j] = *(const short8*)&Bs[s][(wn*4 + j)*1024 + (KS)*512 + lane*8];

  for (int t = 0; t < NT; ++t) {
    int s = t & 1;
    const bool drain = (t >= NT-2);
    {
      LOAD_A(0,0)
      LOAD_B(0)
      if (t+1 < NT) { stageA(s^1, t+1, 1, rbh1); }
      MFMA16(0)
      PHASE_END()
    }
    {
      LOAD_A(0,1)
      if (t+2 < NT) { stageA(s, t+2, 0, rbh0); stageB(s, t+2, 0, w); stageB(s, t+2, 0, 8+w); }
      MFMA16(1)
      PHASE_END()
    }
    {
      LOAD_A(1,0)
      LOAD_B(1)
      if (t+2 < NT) { stageA(s, t+2, 0, rbh1); }
      MFMA16(0)
      PHASE_END()
    }
    {
      LOAD_A(1,1)
      if (t+2 < NT) { stageA(s, t+2, 1, rbh0); stageB(s, t+2, 1, w); stageB(s, t+2, 1, 8+w); }
      MFMA16(1)
      PHASE_END()
    }
  }
#undef PHASE_END
#undef MFMA16
#undef LOAD_A
#undef LOAD_B

  #pragma unroll
  for (int ig = 0; ig < 8; ++ig) {
    #pragma unroll
    for (int j = 0; j < 4; ++j) {
      #pragma unroll
      for (int r = 0; r < 4; ++r) {
        int row = bm + wm*128 + ig*16 + (lane >> 4)*4 + r;
        int col = bn + wn*64 + j*16 + r15;
        C[(size_t)row * ldc + col] = f2bf(acc[ig][j][r]);
      }
    }
  }
}

// ---------------- 128x128 bf16 MFMA GEMM, 2-phase prefetch (out_proj) ----------------
// STAGE(t+1) issued BEFORE compute(t); one __syncthreads per iter (drains vmcnt+lgkm).
// EPI: 0 = none, 2 = + resid[m*ldc+n]; OBF: 1 = bf16 out, 0 = fp32
template<int EPI, int OBF>
__global__ __launch_bounds__(256) void gemm_bf16_kernel(
    const unsigned short* __restrict__ A,   // [M][K] bf16
    const unsigned short* __restrict__ W,   // [N][K] bf16
    void* __restrict__ Cv, int ldc, int K,
    const float* __restrict__ resid)
{
  __shared__ __align__(16) unsigned short Abuf[2][4096];
  __shared__ __align__(16) unsigned short Bbuf[2][4096];
  int tid = threadIdx.x;
  int lane = tid & 63;
  int w = tid >> 6;
  int bm = blockIdx.x * 128;
  int bn = blockIdx.y * 128;
  int wrow = (w >> 1) * 64;
  int wcol = (w & 1) * 64;

  int r15 = lane & 15, g = lane >> 4;
  const unsigned short* Ag0 = A + (size_t)(bm + 2*w*16 + r15) * K + g*8;
  const unsigned short* Ag1 = Ag0 + (size_t)16 * K;
  const unsigned short* Wg0 = W + (size_t)(bn + 2*w*16 + r15) * K + g*8;
  const unsigned short* Wg1 = Wg0 + (size_t)16 * K;

  auto STAGE = [&](int slot, int t) {
    int k0 = t * 32;
    GLL(Ag0 + k0, &Abuf[slot][(2*w  )*512]);
    GLL(Ag1 + k0, &Abuf[slot][(2*w+1)*512]);
    GLL(Wg0 + k0, &Bbuf[slot][(2*w  )*512]);
    GLL(Wg1 + k0, &Bbuf[slot][(2*w+1)*512]);
  };

  f32x4 acc[4][4] = {};
  const int nt = K / 32;

  STAGE(0, 0);
  __syncthreads();

  for (int t = 0; t < nt; ++t) {
    int s = t & 1;
    if (t + 1 < nt) STAGE(s ^ 1, t + 1);

    short8 af[4], bfr[4];
    #pragma unroll
    for (int i = 0; i < 4; ++i)
      af[i] = *(const short8*)&Abuf[s][((wrow >> 4) + i)*512 + lane*8];
    #pragma unroll
    for (int j = 0; j < 4; ++j)
      bfr[j] = *(const short8*)&Bbuf[s][((wcol >> 4) + j)*512 + lane*8];
    #pragma unroll
    for (int i = 0; i < 4; ++i)
      #pragma unroll
      for (int j = 0; j < 4; ++j)
        acc[i][j] = __builtin_amdgcn_mfma_f32_16x16x32_bf16(af[i], bfr[j], acc[i][j], 0, 0, 0);

    __syncthreads();   // drains vmcnt(0)+lgkmcnt(0): next slot staged, reads done
  }

  #pragma unroll
  for (int i = 0; i < 4; ++i) {
    #pragma unroll
    for (int j = 0; j < 4; ++j) {
      #pragma unroll
      for (int r = 0; r < 4; ++r) {
        int row = bm + wrow + i*16 + (lane >> 4)*4 + r;
        int col = bn + wcol + j*16 + (lane & 15);
        float v = acc[i][j][r];
        if (EPI == 2) v += resid[(size_t)row * ldc + col];
        if (OBF) ((unsigned short*)Cv)[(size_t)row * ldc + col] = f2bf(v);
        else     ((float*)Cv)[(size_t)row * ldc + col] = v;
      }
    }
  }
}

// ---------------- x_proj bf16 MFMA, split-K, 2-phase prefetch ----------------
__global__ __launch_bounds__(256) void xproj_bf16_kernel(
    const unsigned short* __restrict__ A,   // [NTOK][D_INNER] bf16 (xc)
    const unsigned short* __restrict__ W,   // [96][D_INNER] bf16
    float* __restrict__ Ppart)              // [XKS][NTOK][96]
{
  __shared__ __align__(16) unsigned short Abuf[2][4096];
  __shared__ __align__(16) unsigned short Bbuf[2][3072];
  int tid = threadIdx.x;
  int lane = tid & 63;
  int w = tid >> 6;
  int bm = blockIdx.x * 128;
  int kc = blockIdx.y;
  const int K = D_INNER;
  int r15 = lane & 15, g = lane >> 4;

  const unsigned short* Ag0 = A + (size_t)(bm + 2*w*16 + r15) * K + g*8 + kc*XKC;
  const unsigned short* Ag1 = Ag0 + (size_t)16 * K;
  const unsigned short* Wg0 = W + (size_t)(w*16 + r15) * K + g*8 + kc*XKC;
  const unsigned short* Wg1 = W + (size_t)((4+w)*16 + r15) * K + g*8 + kc*XKC;

  auto STAGE = [&](int slot, int t) {
    int k0 = t * 32;
    GLL(Ag0 + k0, &Abuf[slot][(2*w  )*512]);
    GLL(Ag1 + k0, &Abuf[slot][(2*w+1)*512]);
    GLL(Wg0 + k0, &Bbuf[slot][w*512]);
    if (w < 2) GLL(Wg1 + k0, &Bbuf[slot][(4+w)*512]);
  };

  f32x4 acc[2][6] = {};
  const int nt = XKC / 32;   // 8

  STAGE(0, 0);
  __syncthreads();

  for (int t = 0; t < nt; ++t) {
    int s = t & 1;
    if (t + 1 < nt) STAGE(s ^ 1, t + 1);

    short8 af[2], bfr[6];
    #pragma unroll
    for (int i = 0; i < 2; ++i)
      af[i] = *(const short8*)&Abuf[s][(2*w + i)*512 + lane*8];
    #pragma unroll
    for (int j = 0; j < 6; ++j)
      bfr[j] = *(const short8*)&Bbuf[s][j*512 + lane*8];
    #pragma unroll
    for (int i = 0; i < 2; ++i)
      #pragma unroll
      for (int j = 0; j < 6; ++j)
        acc[i][j] = __builtin_amdgcn_mfma_f32_16x16x32_bf16(af[i], bfr[j], acc[i][j], 0, 0, 0);

    __syncthreads();
  }

  float* out = Ppart + (size_t)kc * NTOK * 96;
  #pragma unroll
  for (int i = 0; i < 2; ++i) {
    #pragma unroll
    for (int j = 0; j < 6; ++j) {
      #pragma unroll
      for (int r = 0; r < 4; ++r) {
        int row = bm + w*32 + i*16 + (lane >> 4)*4 + r;
        int col = j*16 + (lane & 15);
        out[(size_t)row * 96 + col] = acc[i][j][r];
      }
    }
  }
}

// ---------------- x_proj reduce: sum 8 partials -> dbl fp32 + dt bf16 ----------------
__global__ __launch_bounds__(256) void xproj_reduce_kernel(
    const float* __restrict__ Ppart, float* __restrict__ dbl,
    unsigned short* __restrict__ dtbf)
{
  int idx = blockIdx.x * 256 + threadIdx.x;   // over NTOK*96
  float s = 0.f;
  #pragma unroll
  for (int k = 0; k < XKS; ++k) s += Ppart[(size_t)k * NTOK * 96 + idx];
  dbl[idx] = s;
  int row = idx / 96, col = idx - row * 96;
  if (col < DT_RANK) dtbf[(size_t)row * DT_RANK + col] = f2bf(s);
}

// ---------------- dt_proj + softplus, pure-VALU (K=64 dot) ----------------
// delta[tok][d] = softplus(dot64(dt[tok], Wdt[d]) + bias[d]), bf16 out.
// Block = 8 tokens x 1024 channels (4 waves x 256ch); grid (NTOK/8, 2).
// dt rows staged once in LDS (broadcast reads); stores lane-contiguous 128B.
__global__ __launch_bounds__(256) void dtproj_kernel(
    const unsigned short* __restrict__ dtbf,   // [NTOK][64] bf16
    const unsigned short* __restrict__ Wdt,    // [D_INNER][64] bf16
    const float* __restrict__ bias,            // [D_INNER]
    unsigned short* __restrict__ delta)        // [NTOK][D_INNER] bf16
{
  __shared__ float dt_s[8*64];
  int tg = blockIdx.x;          // token group of 8
  int cg = blockIdx.y;          // channel group of 1024
  int tid = threadIdx.x;
  if (tid < 128) {
    us4 v = *(const us4*)(dtbf + (size_t)tg*8*64 + tid*4);
    #pragma unroll
    for (int i = 0; i < 4; ++i) dt_s[tid*4 + i] = bf2f(v[i]);
  }
  __syncthreads();
  int lane = tid & 63, w = tid >> 6;
  #pragma unroll
  for (int q = 0; q < 4; ++q) {
    int d = cg*1024 + w*256 + q*64 + lane;
    short8 wv[8];
    #pragma unroll
    for (int rg = 0; rg < 8; ++rg)
      wv[rg] = *(const short8*)(Wdt + (size_t)d*64 + rg*8);
    float bd = bias[d];
    float s[8];
    #pragma unroll
    for (int tok = 0; tok < 8; ++tok) s[tok] = bd;
    #pragma unroll
    for (int rg = 0; rg < 8; ++rg) {
      float wf[8];
      #pragma unroll
      for (int j = 0; j < 8; ++j) wf[j] = bf2f((unsigned short)wv[rg][j]);
      #pragma unroll
      for (int tok = 0; tok < 8; ++tok) {
        const float* dp = &dt_s[tok*64 + rg*8];
        #pragma unroll
        for (int j = 0; j < 8; ++j) s[tok] = fmaf(dp[j], wf[j], s[tok]);
      }
    }
    #pragma unroll
    for (int tok = 0; tok < 8; ++tok) {
      float v = s[tok];
      float sp = fmaxf(v, 0.f) + log1pf(__expf(-fabsf(v)));   // stable softplus
      delta[(size_t)(tg*8 + tok) * D_INNER + d] = f2bf(sp);
    }
  }
}

// ---------------- depthwise causal conv1d (k=4) + SiLU, all bf16 ----------------
__global__ __launch_bounds__(256) void conv_silu_kernel(
    const unsigned short* __restrict__ xz, const float* __restrict__ cw,
    const float* __restrict__ cb, unsigned short* __restrict__ xcbf)
{
  int idx = blockIdx.x * 256 + threadIdx.x;   // over NTOK*D_INNER/4
  int dq = idx & (D_INNER/4 - 1);
  int tok = idx >> 9;
  int l = tok & (SEQ - 1);
  int d = dq * 4;
  const unsigned short* xi = xz + (size_t)tok * (2*D_INNER) + d;
  us4 v3 = *(const us4*)xi;
  us4 v2 = l >= 1 ? *(const us4*)(xi - 1*(2*D_INNER)) : (us4)0;
  us4 v1 = l >= 2 ? *(const us4*)(xi - 2*(2*D_INNER)) : (us4)0;
  us4 v0 = l >= 3 ? *(const us4*)(xi - 3*(2*D_INNER)) : (us4)0;
  float4 cbv = *(const float4*)(cb + d);
  float cbx[4] = {cbv.x, cbv.y, cbv.z, cbv.w};
  us4 o;
  #pragma unroll
  for (int j = 0; j < 4; ++j) {
    float4 wv = *(const float4*)(cw + (d + j) * 4);
    float s = cbx[j];
    s = fmaf(bf2f(v0[j]), wv.x, s);
    s = fmaf(bf2f(v1[j]), wv.y, s);
    s = fmaf(bf2f(v2[j]), wv.z, s);
    s = fmaf(bf2f(v3[j]), wv.w, s);
    float v = s / (1.f + __expf(-s));
    o[j] = f2bf(v);
  }
  *(us4*)(xcbf + (size_t)tok * D_INNER + d) = o;
}

// ================= chunked selective scan (bf16 inputs) =================
__global__ __launch_bounds__(256) void scan_pass1(
    const unsigned short* __restrict__ delta, const float* __restrict__ dbl,
    const unsigned short* __restrict__ xc, const float* __restrict__ A_log,
    float* __restrict__ P, float* __restrict__ He)
{
  int blk = blockIdx.x;                 // B*CCH*8 blocks
  int d = (blk & 7) * 256 + threadIdx.x;
  int c = (blk >> 3) & (CCH - 1);
  int b = blk >> 8;
  float Adn[16];
  #pragma unroll
  for (int n = 0; n < 16; ++n) Adn[n] = -__expf(A_log[d*16 + n]);
  float h[16] = {};
  float sdl = 0.f;
  int tok0 = b * SEQ + c * TCH;
  for (int t = 0; t < TCH; ++t) {
    size_t tok = (size_t)(tok0 + t);
    float dl = bf2f(delta[tok * D_INNER + d]);
    float xcv = bf2f(xc[tok * D_INNER + d]);
    float u = dl * xcv;
    const float4* bp = (const float4*)(dbl + tok*96 + 64);
    float4 b0 = bp[0], b1 = bp[1], b2 = bp[2], b3 = bp[3];
    float bv[16] = {b0.x,b0.y,b0.z,b0.w, b1.x,b1.y,b1.z,b1.w,
                    b2.x,b2.y,b2.z,b2.w, b3.x,b3.y,b3.z,b3.w};
    sdl += dl;
    #pragma unroll
    for (int n = 0; n < 16; ++n)
      h[n] = fmaf(__expf(dl * Adn[n]), h[n], u * bv[n]);
  }
  size_t base = ((size_t)(b*CCH + c) * 16) * D_INNER + d;
  #pragma unroll
  for (int n = 0; n < 16; ++n) {
    P [base + (size_t)n * D_INNER] = __expf(Adn[n] * sdl);
    He[base + (size_t)n * D_INNER] = h[n];
  }
}

__global__ __launch_bounds__(256) void scan_pass2(
    const float* __restrict__ P, const float* __restrict__ He,
    float* __restrict__ Hin)
{
  int blk = blockIdx.x;                 // B*16*8 = 256 blocks
  int d = (blk & 7) * 256 + threadIdx.x;
  int n = (blk >> 3) & 15;
  int b = blk >> 7;
  float h = 0.f;
  #pragma unroll 4
  for (int c = 0; c < CCH; ++c) {
    size_t idx = ((size_t)(b*CCH + c) * 16 + n) * D_INNER + d;
    Hin[idx] = h;
    h = fmaf(P[idx], h, He[idx]);
  }
}

__global__ __launch_bounds__(256) void scan_pass3(
    const unsigned short* __restrict__ delta, const float* __restrict__ dbl,
    const unsigned short* __restrict__ xc, const unsigned short* __restrict__ xz,
    const float* __restrict__ A_log, const float* __restrict__ Dp,
    const float* __restrict__ Hin, unsigned short* __restrict__ y)
{
  int blk = blockIdx.x;                 // B*CCH*8 blocks
  int d = (blk & 7) * 256 + threadIdx.x;
  int c = (blk >> 3) & (CCH - 1);
  int b = blk >> 8;
  float Adn[16];
  #pragma unroll
  for (int n = 0; n < 16; ++n) Adn[n] = -__expf(A_log[d*16 + n]);
  float Dpd = Dp[d];
  float h[16];
  size_t base = ((size_t)(b*CCH + c) * 16) * D_INNER + d;
  #pragma unroll
  for (int n = 0; n < 16; ++n) h[n] = Hin[base + (size_t)n * D_INNER];
  int tok0 = b * SEQ + c * TCH;
  for (int t = 0; t < TCH; ++t) {
    size_t tok = (size_t)(tok0 + t);
    float dl = bf2f(delta[tok * D_INNER + d]);
    float xcv = bf2f(xc[tok * D_INNER + d]);
    float u = dl * xcv;
    const float4* bp = (const float4*)(dbl + tok*96 + 64);
    float4 b0 = bp[0], b1 = bp[1], b2 = bp[2], b3 = bp[3];
    float4 c0 = bp[4], c1 = bp[5], c2 = bp[6], c3 = bp[7];
    float bv[16] = {b0.x,b0.y,b0.z,b0.w, b1.x,b1.y,b1.z,b1.w,
                    b2.x,b2.y,b2.z,b2.w, b3.x,b3.y,b3.z,b3.w};
    float cv[16] = {c0.x,c0.y,c0.z,c0.w, c1.x,c1.y,c1.z,c1.w,
                    c2.x,c2.y,c2.z,c2.w, c3.x,c3.y,c3.z,c3.w};
    float z = bf2f(xz[tok * (2*D_INNER) + D_INNER + d]);
    float acc = xcv * Dpd;
    #pragma unroll
    for (int n = 0; n < 16; ++n) {
      h[n] = fmaf(__expf(dl * Adn[n]), h[n], u * bv[n]);
      acc = fmaf(h[n], cv[n], acc);
    }
    float sz = z / (1.f + __expf(-z));
    y[tok * D_INNER + d] = f2bf(acc * sz);
  }
}

// ---------------- launch ----------------
extern "C" void kernel_launch(void* const* d_in, const int* in_sizes, int n_in,
                              void* d_out, int out_size, void* d_ws, size_t ws_size,
                              hipStream_t stream) {
  const float* x         = (const float*)d_in[0];
  const float* norm_w    = (const float*)d_in[1];
  const float* in_proj_w = (const float*)d_in[2];
  const float* conv_w    = (const float*)d_in[3];
  const float* conv_b    = (const float*)d_in[4];
  const float* x_proj_w  = (const float*)d_in[5];
  const float* dt_proj_w = (const float*)d_in[6];
  const float* dt_proj_b = (const float*)d_in[7];
  const float* A_log     = (const float*)d_in[8];
  const float* Dp        = (const float*)d_in[9];
  const float* out_proj_w= (const float*)d_in[10];
  float* out = (float*)d_out;

  // Workspace layout — no aliasing, total ~142 MB:
  char* ws = (char*)d_ws;
  unsigned short* xz_bf   = (unsigned short*)(ws);                 //   0.. 32 MB
  unsigned short* xc_bf   = (unsigned short*)(ws + ( 32ull<<20));  //  32.. 48 MB
  float*          dbl     = (float*)(ws + ( 48ull<<20));           //  48.. 50 MB
  unsigned short* delta_bf= (unsigned short*)(ws + ( 50ull<<20));  //  50.. 66 MB
  unsigned short* xn_bf   = (unsigned short*)(ws + ( 66ull<<20));  //  66.. 74 MB
  unsigned short* w_in_bf = (unsigned short*)(ws + ( 74ull<<20));  //  74.. 82 MB
  unsigned short* w_out_bf= (unsigned short*)(ws + ( 82ull<<20));  //  82.. 86 MB
  unsigned short* w_xp_bf = (unsigned short*)(ws + ( 86ull<<20));  //  86..86.5 MB
  unsigned short* w_dt_bf = (unsigned short*)(ws + ( 87ull<<20));  //  87..87.5 MB
  unsigned short* dtbf    = (unsigned short*)(ws + ( 88ull<<20));  //  88..88.5 MB
  float*          Ppart   = (float*)(ws + ( 89ull<<20));           //  89..101.6 MB
  float*          Pst     = (float*)(ws + (102ull<<20));           // 102..110 MB
  float*          Hest    = (float*)(ws + (110ull<<20));           // 110..118 MB
  float*          Hin     = (float*)(ws + (118ull<<20));           // 118..126 MB
  unsigned short* yb_bf   = (unsigned short*)(ws + (126ull<<20));  // 126..142 MB

  // 1. RMSNorm -> bf16
  rmsnorm_kernel<<<NTOK, 256, 0, stream>>>(x, norm_w, xn_bf);

  // 1b. all weight conversions fp32 -> bf16, one launch
  f2bf4_kernel<<<4096+2048+192+128, 256, 0, stream>>>(
      in_proj_w, w_in_bf, 4096,
      out_proj_w, w_out_bf, 2048,
      x_proj_w, w_xp_bf, 192,
      dt_proj_w, w_dt_bf);

  // 2. in_proj (256x256 8-phase bf16 MFMA) -> xz bf16
  {
    dim3 g(NTOK/256, (2*D_INNER)/256);   // (16,16)
    gemm256_bf16_kernel<D_MODEL/64><<<g, 512, 0, stream>>>(xn_bf, w_in_bf, xz_bf, 2*D_INNER);
  }

  // 3. depthwise conv + SiLU (bf16 in/out)
  conv_silu_kernel<<<(NTOK*D_INNER/4)/256, 256, 0, stream>>>(xz_bf, conv_w, conv_b, xc_bf);

  // 4. x_proj (bf16 MFMA, split-K=8, 2-phase) + reduce -> dbl fp32, dt bf16
  {
    dim3 g(NTOK/128, XKS);
    xproj_bf16_kernel<<<g, 256, 0, stream>>>(xc_bf, w_xp_bf, Ppart);
    xproj_reduce_kernel<<<(NTOK*96)/256, 256, 0, stream>>>(Ppart, dbl, dtbf);
  }

  // 5. dt_proj + softplus (pure VALU) -> delta bf16
  {
    dim3 g(NTOK/8, 2);
    dtproj_kernel<<<g, 256, 0, stream>>>(dtbf, w_dt_bf, dt_proj_b, delta_bf);
  }

  // 6. chunked selective scan -> bf16 y
  scan_pass1<<<BATCH*CCH*8, 256, 0, stream>>>(delta_bf, dbl, xc_bf, A_log, Pst, Hest);
  scan_pass2<<<BATCH*16*8, 256, 0, stream>>>(Pst, Hest, Hin);
  scan_pass3<<<BATCH*CCH*8, 256, 0, stream>>>(delta_bf, dbl, xc_bf, xz_bf, A_log, Dp, Hin, yb_bf);

  // 7. out_proj (128² 2-phase bf16 MFMA) + residual -> fp32 out
  {
    dim3 g(NTOK/128, D_MODEL/128);
    gemm_bf16_kernel<2,0><<<g, 256, 0, stream>>>(yb_bf, w_out_bf, out, D_MODEL, D_INNER, x);
  }
}

// Round 10
// 364.952 us; speedup vs baseline: 1.1265x; 1.1265x over previous
//
#include <hip/hip_runtime.h>
#include <hip/hip_bf16.h>
#include <math.h>

#define D_MODEL 1024
#define D_STATE 16
#define D_CONV 4
#define D_INNER 2048
#define DT_RANK 64
#define BATCH 2
#define SEQ 2048
#define NTOK (BATCH*SEQ)   // 4096
#define EPS 1e-5f
#define CCH 32             // scan chunks per sequence
#define TCH (SEQ/CCH)      // 64 tokens per chunk
#define XKS 8              // x_proj split-K factor
#define XKC (D_INNER/XKS)  // 256 K per chunk

typedef __attribute__((ext_vector_type(8))) short short8;
typedef __attribute__((ext_vector_type(4))) float f32x4;
typedef __attribute__((ext_vector_type(4))) unsigned short us4;

__device__ inline unsigned short f2bf(float f) {
  union { __hip_bfloat16 h; unsigned short u; } c;
  c.h = __float2bfloat16(f);
  return c.u;
}
__device__ inline float bf2f(unsigned short u) {
  union { unsigned int i; float f; } c;
  c.i = ((unsigned int)u) << 16;
  return c.f;
}

#define GLL(gp, lp) __builtin_amdgcn_global_load_lds( \
    (const __attribute__((address_space(1))) void*)(gp), \
    (__attribute__((address_space(3))) void*)(lp), 16, 0, 0)

// ---------------- fused fp32 -> bf16 convert for the 4 weight tensors ----------------
__global__ __launch_bounds__(256) void f2bf4_kernel(
    const float* __restrict__ i0, unsigned short* __restrict__ o0, int b0,
    const float* __restrict__ i1, unsigned short* __restrict__ o1, int b1,
    const float* __restrict__ i2, unsigned short* __restrict__ o2, int b2,
    const float* __restrict__ i3, unsigned short* __restrict__ o3)
{
  int blk = blockIdx.x;
  const float* in; unsigned short* out; int base;
  if (blk < b0)           { in = i0; out = o0; base = blk; }
  else if (blk < b0+b1)   { in = i1; out = o1; base = blk - b0; }
  else if (blk < b0+b1+b2){ in = i2; out = o2; base = blk - b0 - b1; }
  else                    { in = i3; out = o3; base = blk - b0 - b1 - b2; }
  int i = (base*256 + threadIdx.x)*4;
  float4 v = *(const float4*)(in + i);
  us4 o;
  o[0] = f2bf(v.x); o[1] = f2bf(v.y); o[2] = f2bf(v.z); o[3] = f2bf(v.w);
  *(us4*)(out + i) = o;
}

// ---------------- RMSNorm: one block per token, bf16 output ----------------
__global__ __launch_bounds__(256) void rmsnorm_kernel(const float* __restrict__ x,
                                                      const float* __restrict__ w,
                                                      unsigned short* __restrict__ xn) {
  int tok = blockIdx.x;
  const float* xr = x + (size_t)tok * D_MODEL;
  unsigned short* xo = xn + (size_t)tok * D_MODEL;
  int t = threadIdx.x;
  float4 v = ((const float4*)xr)[t];
  float ss = v.x*v.x + v.y*v.y + v.z*v.z + v.w*v.w;
  #pragma unroll
  for (int off = 32; off > 0; off >>= 1) ss += __shfl_down(ss, off, 64);
  __shared__ float wsum[4];
  __shared__ float rinv_s;
  int lane = t & 63, wv = t >> 6;
  if (lane == 0) wsum[wv] = ss;
  __syncthreads();
  if (t == 0) {
    float tot = wsum[0] + wsum[1] + wsum[2] + wsum[3];
    rinv_s = 1.0f / sqrtf(tot / (float)D_MODEL + EPS);
  }
  __syncthreads();
  float rinv = rinv_s;
  float4 g = ((const float4*)w)[t];
  us4 o;
  o[0] = f2bf(v.x * rinv * g.x);
  o[1] = f2bf(v.y * rinv * g.y);
  o[2] = f2bf(v.z * rinv * g.z);
  o[3] = f2bf(v.w * rinv * g.w);
  *(us4*)(xo + t*4) = o;
}

// ================== 256x256 8-phase bf16 MFMA GEMM (in_proj) ==================
// (verified in R8 bench — see R7 notes)
template<int NT>   // K = NT*64
__global__ __launch_bounds__(512) void gemm256_bf16_kernel(
    const unsigned short* __restrict__ A,   // [M][K]
    const unsigned short* __restrict__ W,   // [N][K]
    unsigned short* __restrict__ C, int ldc)
{
  const int K = NT*64;
  __shared__ __align__(16) unsigned short As[2][16384];
  __shared__ __align__(16) unsigned short Bs[2][16384];
  int tid = threadIdx.x;
  int lane = tid & 63;
  int w = tid >> 6;          // 0..7
  int wm = w >> 2, wn = w & 3;
  int bm = blockIdx.x * 256;
  int bn = blockIdx.y * 256;
  int r15 = lane & 15, g8 = (lane >> 4) * 8;
  int rbh0 = (w & 3) + (w >> 2) * 8;
  int rbh1 = rbh0 + 4;

  auto stageA = [&](int slot, int tile, int ks, int rb) {
    const unsigned short* src = A + (size_t)(bm + rb*16 + r15) * K + tile*64 + ks*32 + g8;
    GLL(src, &As[slot][rb*1024 + ks*512]);
  };
  auto stageB = [&](int slot, int tile, int ks, int cb) {
    const unsigned short* src = W + (size_t)(bn + cb*16 + r15) * K + tile*64 + ks*32 + g8;
    GLL(src, &Bs[slot][cb*1024 + ks*512]);
  };

  stageA(0,0,0,rbh0); stageB(0,0,0,w); stageB(0,0,0,8+w);
  stageA(0,0,0,rbh1);
  stageA(0,0,1,rbh0); stageB(0,0,1,w); stageB(0,0,1,8+w);
  stageA(0,0,1,rbh1);
  stageA(1,1,0,rbh0); stageB(1,1,0,w); stageB(1,1,0,8+w);
  stageA(1,1,0,rbh1);
  stageA(1,1,1,rbh0); stageB(1,1,1,w); stageB(1,1,1,8+w);
  asm volatile("s_waitcnt vmcnt(7)" ::: "memory");
  __builtin_amdgcn_s_barrier();
  __builtin_amdgcn_sched_barrier(0);

  f32x4 acc[8][4] = {};
  short8 bfr[4];

#define PHASE_END()                                                      \
  if (drain) { asm volatile("s_waitcnt vmcnt(0)" ::: "memory"); }        \
  else       { asm volatile("s_waitcnt vmcnt(12)" ::: "memory"); }       \
  __builtin_amdgcn_s_barrier();                                          \
  __builtin_amdgcn_sched_barrier(0);

#define MFMA16(IH)                                                       \
  __builtin_amdgcn_s_setprio(1);                                         \
  _Pragma("unroll")                                                      \
  for (int ii = 0; ii < 4; ++ii) {                                       \
    _Pragma("unroll")                                                    \
    for (int j = 0; j < 4; ++j)                                          \
      acc[(IH)*4+ii][j] = __builtin_amdgcn_mfma_f32_16x16x32_bf16(       \
          af[ii], bfr[j], acc[(IH)*4+ii][j], 0, 0, 0);                   \
  }                                                                      \
  __builtin_amdgcn_s_setprio(0);

#define LOAD_A(KS, IH)                                                   \
  short8 af[4];                                                          \
  _Pragma("unroll")                                                      \
  for (int ii = 0; ii < 4; ++ii)                                         \
    af[ii] = *(const short8*)&As[s][(wm*8 + (IH)*4 + ii)*1024 + (KS)*512 + lane*8];

#define LOAD_B(KS)                                                       \
  _Pragma("unroll")                                                      \
  for (int j = 0; j < 4; ++j)                                            \
    bfr[j] = *(const short8*)&Bs[s][(wn*4 + j)*1024 + (KS)*512 + lane*8];

  for (int t = 0; t < NT; ++t) {
    int s = t & 1;
    const bool drain = (t >= NT-2);
    {
      LOAD_A(0,0)
      LOAD_B(0)
      if (t+1 < NT) { stageA(s^1, t+1, 1, rbh1); }
      MFMA16(0)
      PHASE_END()
    }
    {
      LOAD_A(0,1)
      if (t+2 < NT) { stageA(s, t+2, 0, rbh0); stageB(s, t+2, 0, w); stageB(s, t+2, 0, 8+w); }
      MFMA16(1)
      PHASE_END()
    }
    {
      LOAD_A(1,0)
      LOAD_B(1)
      if (t+2 < NT) { stageA(s, t+2, 0, rbh1); }
      MFMA16(0)
      PHASE_END()
    }
    {
      LOAD_A(1,1)
      if (t+2 < NT) { stageA(s, t+2, 1, rbh0); stageB(s, t+2, 1, w); stageB(s, t+2, 1, 8+w); }
      MFMA16(1)
      PHASE_END()
    }
  }
#undef PHASE_END
#undef MFMA16
#undef LOAD_A
#undef LOAD_B

  #pragma unroll
  for (int ig = 0; ig < 8; ++ig) {
    #pragma unroll
    for (int j = 0; j < 4; ++j) {
      #pragma unroll
      for (int r = 0; r < 4; ++r) {
        int row = bm + wm*128 + ig*16 + (lane >> 4)*4 + r;
        int col = bn + wn*64 + j*16 + r15;
        C[(size_t)row * ldc + col] = f2bf(acc[ig][j][r]);
      }
    }
  }
}

// ---------------- 128x128 bf16 MFMA GEMM (out_proj) — R7-verified single-buffer ----
// EPI: 0 = none, 2 = + resid[m*ldc+n]; OBF: 1 = bf16 out, 0 = fp32
template<int EPI, int OBF>
__global__ __launch_bounds__(256) void gemm_bf16_kernel(
    const unsigned short* __restrict__ A,   // [M][K] bf16
    const unsigned short* __restrict__ W,   // [N][K] bf16
    void* __restrict__ Cv, int ldc, int K,
    const float* __restrict__ resid)
{
  __shared__ __align__(16) unsigned short Abuf[8*64*8];
  __shared__ __align__(16) unsigned short Bbuf[8*64*8];
  int tid = threadIdx.x;
  int lane = tid & 63;
  int w = tid >> 6;
  int bm = blockIdx.x * 128;
  int bn = blockIdx.y * 128;
  int wrow = (w >> 1) * 64;
  int wcol = (w & 1) * 64;

  int r15 = lane & 15, g = lane >> 4;
  const unsigned short* Ag0 = A + (size_t)(bm + 2*w*16 + r15) * K + g*8;
  const unsigned short* Ag1 = Ag0 + (size_t)16 * K;
  const unsigned short* Wg0 = W + (size_t)(bn + 2*w*16 + r15) * K + g*8;
  const unsigned short* Wg1 = Wg0 + (size_t)16 * K;
  unsigned short* Al0 = &Abuf[(2*w  )*512];
  unsigned short* Al1 = &Abuf[(2*w+1)*512];
  unsigned short* Bl0 = &Bbuf[(2*w  )*512];
  unsigned short* Bl1 = &Bbuf[(2*w+1)*512];

  f32x4 acc[4][4] = {};

  for (int k0 = 0; k0 < K; k0 += 32) {
    __syncthreads();
    GLL(Ag0 + k0, Al0);
    GLL(Ag1 + k0, Al1);
    GLL(Wg0 + k0, Bl0);
    GLL(Wg1 + k0, Bl1);
    __syncthreads();

    short8 af[4], bfr[4];
    #pragma unroll
    for (int i = 0; i < 4; ++i)
      af[i] = *(const short8*)&Abuf[((wrow >> 4) + i)*512 + lane*8];
    #pragma unroll
    for (int j = 0; j < 4; ++j)
      bfr[j] = *(const short8*)&Bbuf[((wcol >> 4) + j)*512 + lane*8];
    #pragma unroll
    for (int i = 0; i < 4; ++i)
      #pragma unroll
      for (int j = 0; j < 4; ++j)
        acc[i][j] = __builtin_amdgcn_mfma_f32_16x16x32_bf16(af[i], bfr[j], acc[i][j], 0, 0, 0);
  }

  #pragma unroll
  for (int i = 0; i < 4; ++i) {
    #pragma unroll
    for (int j = 0; j < 4; ++j) {
      #pragma unroll
      for (int r = 0; r < 4; ++r) {
        int row = bm + wrow + i*16 + (lane >> 4)*4 + r;
        int col = bn + wcol + j*16 + (lane & 15);
        float v = acc[i][j][r];
        if (EPI == 2) v += resid[(size_t)row * ldc + col];
        if (OBF) ((unsigned short*)Cv)[(size_t)row * ldc + col] = f2bf(v);
        else     ((float*)Cv)[(size_t)row * ldc + col] = v;
      }
    }
  }
}

// ---------------- x_proj bf16 MFMA, split-K — R7-verified single-buffer ----------
__global__ __launch_bounds__(256) void xproj_bf16_kernel(
    const unsigned short* __restrict__ A,   // [NTOK][D_INNER] bf16 (xc)
    const unsigned short* __restrict__ W,   // [96][D_INNER] bf16
    float* __restrict__ Ppart)              // [XKS][NTOK][96]
{
  __shared__ __align__(16) unsigned short Abuf[8*512];
  __shared__ __align__(16) unsigned short Bbuf[6*512];
  int tid = threadIdx.x;
  int lane = tid & 63;
  int w = tid >> 6;
  int bm = blockIdx.x * 128;
  int kc = blockIdx.y;
  const int K = D_INNER;
  int r15 = lane & 15, g = lane >> 4;

  const unsigned short* Ag0 = A + (size_t)(bm + 2*w*16 + r15) * K + g*8 + kc*XKC;
  const unsigned short* Ag1 = Ag0 + (size_t)16 * K;
  const unsigned short* Wg0 = W + (size_t)(w*16 + r15) * K + g*8 + kc*XKC;
  const unsigned short* Wg1 = W + (size_t)((4+w)*16 + r15) * K + g*8 + kc*XKC;
  unsigned short* Al0 = &Abuf[(2*w  )*512];
  unsigned short* Al1 = &Abuf[(2*w+1)*512];
  unsigned short* Bl0 = &Bbuf[w*512];
  unsigned short* Bl1 = &Bbuf[(4+w)*512];

  f32x4 acc[2][6] = {};

  for (int k0 = 0; k0 < XKC; k0 += 32) {
    __syncthreads();
    GLL(Ag0 + k0, Al0);
    GLL(Ag1 + k0, Al1);
    GLL(Wg0 + k0, Bl0);
    if (w < 2) GLL(Wg1 + k0, Bl1);
    __syncthreads();

    short8 af[2], bfr[6];
    #pragma unroll
    for (int i = 0; i < 2; ++i)
      af[i] = *(const short8*)&Abuf[(2*w + i)*512 + lane*8];
    #pragma unroll
    for (int j = 0; j < 6; ++j)
      bfr[j] = *(const short8*)&Bbuf[j*512 + lane*8];
    #pragma unroll
    for (int i = 0; i < 2; ++i)
      #pragma unroll
      for (int j = 0; j < 6; ++j)
        acc[i][j] = __builtin_amdgcn_mfma_f32_16x16x32_bf16(af[i], bfr[j], acc[i][j], 0, 0, 0);
  }

  float* out = Ppart + (size_t)kc * NTOK * 96;
  #pragma unroll
  for (int i = 0; i < 2; ++i) {
    #pragma unroll
    for (int j = 0; j < 6; ++j) {
      #pragma unroll
      for (int r = 0; r < 4; ++r) {
        int row = bm + w*32 + i*16 + (lane >> 4)*4 + r;
        int col = j*16 + (lane & 15);
        out[(size_t)row * 96 + col] = acc[i][j][r];
      }
    }
  }
}

// ---------------- x_proj reduce: sum 8 partials -> dbl fp32 ----------------
__global__ __launch_bounds__(256) void xproj_reduce_kernel(
    const float* __restrict__ Ppart, float* __restrict__ dbl)
{
  int idx = blockIdx.x * 256 + threadIdx.x;   // over NTOK*96
  float s = 0.f;
  #pragma unroll
  for (int k = 0; k < XKS; ++k) s += Ppart[(size_t)k * NTOK * 96 + idx];
  dbl[idx] = s;
}

// ---------------- dt_proj + softplus, VALU v2 ----------------
// delta[tok][d] = softplus(dot64(dt[tok], Wdt[d]) + bias[d]), bf16 out.
// Block = 256 d-channels (1/lane, coalesced) x 16 tokens; grid (8, 256).
// W-tile 256x64 bf16 in LDS (row stride 68: b64 reads 2-way = free);
// dt fp32 from dbl (cols 0..63) in LDS, consumed as wave-broadcast float4.
__global__ __launch_bounds__(256) void dtproj_kernel(
    const float* __restrict__ dbl,            // [NTOK][96] fp32; dt = cols 0..63
    const unsigned short* __restrict__ Wdt,   // [D_INNER][64] bf16
    const float* __restrict__ bias,           // [D_INNER]
    unsigned short* __restrict__ delta)       // [NTOK][D_INNER] bf16
{
  __shared__ unsigned short Wl[256*68];       // padded stride 68 (34KB)
  __shared__ float dts[16][64];
  int tid = threadIdx.x;
  int dBase = blockIdx.x * 256;
  int tok0 = blockIdx.y * 16;

  // cooperative W-tile load: 256x64 bf16, coalesced global, b64 LDS writes
  #pragma unroll
  for (int i = 0; i < 8; ++i) {
    int idx = i*256 + tid;          // 0..2047 over (row, kc8)
    int row = idx >> 3, kc = (idx & 7) * 8;
    const us4* src = (const us4*)(Wdt + (size_t)(dBase + row)*64 + kc);
    us4 lo = src[0], hi = src[1];
    *(us4*)&Wl[row*68 + kc    ] = lo;
    *(us4*)&Wl[row*68 + kc + 4] = hi;
  }
  // dt tile: 16 tok x 64 f32
  {
    int t = tid >> 4, kq = tid & 15;
    *(float4*)&dts[t][kq*4] = *(const float4*)(dbl + (size_t)(tok0 + t)*96 + kq*4);
  }
  __syncthreads();

  int d = dBase + tid;
  float s[16];
  float bd = bias[d];
  #pragma unroll
  for (int t = 0; t < 16; ++t) s[t] = bd;

  #pragma unroll
  for (int j = 0; j < 16; ++j) {      // 4 k per step
    us4 wv = *(const us4*)&Wl[tid*68 + j*4];   // b64, 2-way bank = free
    float w0 = bf2f(wv[0]), w1 = bf2f(wv[1]), w2 = bf2f(wv[2]), w3 = bf2f(wv[3]);
    #pragma unroll
    for (int t = 0; t < 16; ++t) {
      float4 dv = *(const float4*)&dts[t][j*4];  // broadcast
      s[t] = fmaf(dv.x, w0, s[t]);
      s[t] = fmaf(dv.y, w1, s[t]);
      s[t] = fmaf(dv.z, w2, s[t]);
      s[t] = fmaf(dv.w, w3, s[t]);
    }
  }

  #pragma unroll
  for (int t = 0; t < 16; ++t) {
    float v = s[t];
    float sp = (v > 20.f) ? v : __logf(1.f + __expf(v));   // fast stable softplus
    delta[(size_t)(tok0 + t) * D_INNER + d] = f2bf(sp);    // lane-contiguous store
  }
}

// ---------------- depthwise causal conv1d (k=4) + SiLU, all bf16 ----------------
__global__ __launch_bounds__(256) void conv_silu_kernel(
    const unsigned short* __restrict__ xz, const float* __restrict__ cw,
    const float* __restrict__ cb, unsigned short* __restrict__ xcbf)
{
  int idx = blockIdx.x * 256 + threadIdx.x;   // over NTOK*D_INNER/4
  int dq = idx & (D_INNER/4 - 1);
  int tok = idx >> 9;
  int l = tok & (SEQ - 1);
  int d = dq * 4;
  const unsigned short* xi = xz + (size_t)tok * (2*D_INNER) + d;
  us4 v3 = *(const us4*)xi;
  us4 v2 = l >= 1 ? *(const us4*)(xi - 1*(2*D_INNER)) : (us4)0;
  us4 v1 = l >= 2 ? *(const us4*)(xi - 2*(2*D_INNER)) : (us4)0;
  us4 v0 = l >= 3 ? *(const us4*)(xi - 3*(2*D_INNER)) : (us4)0;
  float4 cbv = *(const float4*)(cb + d);
  float cbx[4] = {cbv.x, cbv.y, cbv.z, cbv.w};
  us4 o;
  #pragma unroll
  for (int j = 0; j < 4; ++j) {
    float4 wv = *(const float4*)(cw + (d + j) * 4);
    float s = cbx[j];
    s = fmaf(bf2f(v0[j]), wv.x, s);
    s = fmaf(bf2f(v1[j]), wv.y, s);
    s = fmaf(bf2f(v2[j]), wv.z, s);
    s = fmaf(bf2f(v3[j]), wv.w, s);
    float v = s / (1.f + __expf(-s));
    o[j] = f2bf(v);
  }
  *(us4*)(xcbf + (size_t)tok * D_INNER + d) = o;
}

// ================= chunked selective scan (bf16 inputs) =================
__global__ __launch_bounds__(256) void scan_pass1(
    const unsigned short* __restrict__ delta, const float* __restrict__ dbl,
    const unsigned short* __restrict__ xc, const float* __restrict__ A_log,
    float* __restrict__ P, float* __restrict__ He)
{
  int blk = blockIdx.x;                 // B*CCH*8 blocks
  int d = (blk & 7) * 256 + threadIdx.x;
  int c = (blk >> 3) & (CCH - 1);
  int b = blk >> 8;
  float Adn[16];
  #pragma unroll
  for (int n = 0; n < 16; ++n) Adn[n] = -__expf(A_log[d*16 + n]);
  float h[16] = {};
  float sdl = 0.f;
  int tok0 = b * SEQ + c * TCH;
  for (int t = 0; t < TCH; ++t) {
    size_t tok = (size_t)(tok0 + t);
    float dl = bf2f(delta[tok * D_INNER + d]);
    float xcv = bf2f(xc[tok * D_INNER + d]);
    float u = dl * xcv;
    const float4* bp = (const float4*)(dbl + tok*96 + 64);
    float4 b0 = bp[0], b1 = bp[1], b2 = bp[2], b3 = bp[3];
    float bv[16] = {b0.x,b0.y,b0.z,b0.w, b1.x,b1.y,b1.z,b1.w,
                    b2.x,b2.y,b2.z,b2.w, b3.x,b3.y,b3.z,b3.w};
    sdl += dl;
    #pragma unroll
    for (int n = 0; n < 16; ++n)
      h[n] = fmaf(__expf(dl * Adn[n]), h[n], u * bv[n]);
  }
  size_t base = ((size_t)(b*CCH + c) * 16) * D_INNER + d;
  #pragma unroll
  for (int n = 0; n < 16; ++n) {
    P [base + (size_t)n * D_INNER] = __expf(Adn[n] * sdl);
    He[base + (size_t)n * D_INNER] = h[n];
  }
}

__global__ __launch_bounds__(256) void scan_pass2(
    const float* __restrict__ P, const float* __restrict__ He,
    float* __restrict__ Hin)
{
  int blk = blockIdx.x;                 // B*16*8 = 256 blocks
  int d = (blk & 7) * 256 + threadIdx.x;
  int n = (blk >> 3) & 15;
  int b = blk >> 7;
  float h = 0.f;
  #pragma unroll 4
  for (int c = 0; c < CCH; ++c) {
    size_t idx = ((size_t)(b*CCH + c) * 16 + n) * D_INNER + d;
    Hin[idx] = h;
    h = fmaf(P[idx], h, He[idx]);
  }
}

__global__ __launch_bounds__(256) void scan_pass3(
    const unsigned short* __restrict__ delta, const float* __restrict__ dbl,
    const unsigned short* __restrict__ xc, const unsigned short* __restrict__ xz,
    const float* __restrict__ A_log, const float* __restrict__ Dp,
    const float* __restrict__ Hin, unsigned short* __restrict__ y)
{
  int blk = blockIdx.x;                 // B*CCH*8 blocks
  int d = (blk & 7) * 256 + threadIdx.x;
  int c = (blk >> 3) & (CCH - 1);
  int b = blk >> 8;
  float Adn[16];
  #pragma unroll
  for (int n = 0; n < 16; ++n) Adn[n] = -__expf(A_log[d*16 + n]);
  float Dpd = Dp[d];
  float h[16];
  size_t base = ((size_t)(b*CCH + c) * 16) * D_INNER + d;
  #pragma unroll
  for (int n = 0; n < 16; ++n) h[n] = Hin[base + (size_t)n * D_INNER];
  int tok0 = b * SEQ + c * TCH;
  for (int t = 0; t < TCH; ++t) {
    size_t tok = (size_t)(tok0 + t);
    float dl = bf2f(delta[tok * D_INNER + d]);
    float xcv = bf2f(xc[tok * D_INNER + d]);
    float u = dl * xcv;
    const float4* bp = (const float4*)(dbl + tok*96 + 64);
    float4 b0 = bp[0], b1 = bp[1], b2 = bp[2], b3 = bp[3];
    float4 c0 = bp[4], c1 = bp[5], c2 = bp[6], c3 = bp[7];
    float bv[16] = {b0.x,b0.y,b0.z,b0.w, b1.x,b1.y,b1.z,b1.w,
                    b2.x,b2.y,b2.z,b2.w, b3.x,b3.y,b3.z,b3.w};
    float cv[16] = {c0.x,c0.y,c0.z,c0.w, c1.x,c1.y,c1.z,c1.w,
                    c2.x,c2.y,c2.z,c2.w, c3.x,c3.y,c3.z,c3.w};
    float z = bf2f(xz[tok * (2*D_INNER) + D_INNER + d]);
    float acc = xcv * Dpd;
    #pragma unroll
    for (int n = 0; n < 16; ++n) {
      h[n] = fmaf(__expf(dl * Adn[n]), h[n], u * bv[n]);
      acc = fmaf(h[n], cv[n], acc);
    }
    float sz = z / (1.f + __expf(-z));
    y[tok * D_INNER + d] = f2bf(acc * sz);
  }
}

// ---------------- launch ----------------
extern "C" void kernel_launch(void* const* d_in, const int* in_sizes, int n_in,
                              void* d_out, int out_size, void* d_ws, size_t ws_size,
                              hipStream_t stream) {
  const float* x         = (const float*)d_in[0];
  const float* norm_w    = (const float*)d_in[1];
  const float* in_proj_w = (const float*)d_in[2];
  const float* conv_w    = (const float*)d_in[3];
  const float* conv_b    = (const float*)d_in[4];
  const float* x_proj_w  = (const float*)d_in[5];
  const float* dt_proj_w = (const float*)d_in[6];
  const float* dt_proj_b = (const float*)d_in[7];
  const float* A_log     = (const float*)d_in[8];
  const float* Dp        = (const float*)d_in[9];
  const float* out_proj_w= (const float*)d_in[10];
  float* out = (float*)d_out;

  // Workspace layout — no aliasing, total ~142 MB:
  char* ws = (char*)d_ws;
  unsigned short* xz_bf   = (unsigned short*)(ws);                 //   0.. 32 MB
  unsigned short* xc_bf   = (unsigned short*)(ws + ( 32ull<<20));  //  32.. 48 MB
  float*          dbl     = (float*)(ws + ( 48ull<<20));           //  48.. 50 MB
  unsigned short* delta_bf= (unsigned short*)(ws + ( 50ull<<20));  //  50.. 66 MB
  unsigned short* xn_bf   = (unsigned short*)(ws + ( 66ull<<20));  //  66.. 74 MB
  unsigned short* w_in_bf = (unsigned short*)(ws + ( 74ull<<20));  //  74.. 82 MB
  unsigned short* w_out_bf= (unsigned short*)(ws + ( 82ull<<20));  //  82.. 86 MB
  unsigned short* w_xp_bf = (unsigned short*)(ws + ( 86ull<<20));  //  86..86.5 MB
  unsigned short* w_dt_bf = (unsigned short*)(ws + ( 87ull<<20));  //  87..87.5 MB
  float*          Ppart   = (float*)(ws + ( 89ull<<20));           //  89..101.6 MB
  float*          Pst     = (float*)(ws + (102ull<<20));           // 102..110 MB
  float*          Hest    = (float*)(ws + (110ull<<20));           // 110..118 MB
  float*          Hin     = (float*)(ws + (118ull<<20));           // 118..126 MB
  unsigned short* yb_bf   = (unsigned short*)(ws + (126ull<<20));  // 126..142 MB

  // 1. RMSNorm -> bf16
  rmsnorm_kernel<<<NTOK, 256, 0, stream>>>(x, norm_w, xn_bf);

  // 1b. all weight conversions fp32 -> bf16, one launch
  f2bf4_kernel<<<4096+2048+192+128, 256, 0, stream>>>(
      in_proj_w, w_in_bf, 4096,
      out_proj_w, w_out_bf, 2048,
      x_proj_w, w_xp_bf, 192,
      dt_proj_w, w_dt_bf);

  // 2. in_proj (256x256 8-phase bf16 MFMA) -> xz bf16
  {
    dim3 g(NTOK/256, (2*D_INNER)/256);   // (16,16)
    gemm256_bf16_kernel<D_MODEL/64><<<g, 512, 0, stream>>>(xn_bf, w_in_bf, xz_bf, 2*D_INNER);
  }

  // 3. depthwise conv + SiLU (bf16 in/out)
  conv_silu_kernel<<<(NTOK*D_INNER/4)/256, 256, 0, stream>>>(xz_bf, conv_w, conv_b, xc_bf);

  // 4. x_proj (bf16 MFMA, split-K=8) + reduce -> dbl fp32
  {
    dim3 g(NTOK/128, XKS);
    xproj_bf16_kernel<<<g, 256, 0, stream>>>(xc_bf, w_xp_bf, Ppart);
    xproj_reduce_kernel<<<(NTOK*96)/256, 256, 0, stream>>>(Ppart, dbl);
  }

  // 5. dt_proj + softplus (VALU v2) -> delta bf16
  {
    dim3 g(D_INNER/256, NTOK/16);   // (8, 256)
    dtproj_kernel<<<g, 256, 0, stream>>>(dbl, w_dt_bf, dt_proj_b, delta_bf);
  }

  // 6. chunked selective scan -> bf16 y
  scan_pass1<<<BATCH*CCH*8, 256, 0, stream>>>(delta_bf, dbl, xc_bf, A_log, Pst, Hest);
  scan_pass2<<<BATCH*16*8, 256, 0, stream>>>(Pst, Hest, Hin);
  scan_pass3<<<BATCH*CCH*8, 256, 0, stream>>>(delta_bf, dbl, xc_bf, xz_bf, A_log, Dp, Hin, yb_bf);

  // 7. out_proj (128² bf16 MFMA) + residual -> fp32 out
  {
    dim3 g(NTOK/128, D_MODEL/128);
    gemm_bf16_kernel<2,0><<<g, 256, 0, stream>>>(yb_bf, w_out_bf, out, D_MODEL, D_INNER, x);
  }
}

// Round 11
// 345.232 us; speedup vs baseline: 1.1908x; 1.0571x over previous
//
#include <hip/hip_runtime.h>
#include <hip/hip_bf16.h>
#include <math.h>

#define D_MODEL 1024
#define D_STATE 16
#define D_CONV 4
#define D_INNER 2048
#define DT_RANK 64
#define BATCH 2
#define SEQ 2048
#define NTOK (BATCH*SEQ)   // 4096
#define EPS 1e-5f
#define CCH 32             // scan chunks per sequence
#define TCH (SEQ/CCH)      // 64 tokens per chunk
#define XKS 8              // x_proj split-K factor
#define XKC (D_INNER/XKS)  // 256 K per chunk

typedef __attribute__((ext_vector_type(8))) short short8;
typedef __attribute__((ext_vector_type(4))) float f32x4;
typedef __attribute__((ext_vector_type(4))) unsigned short us4;

__device__ inline unsigned short f2bf(float f) {
  union { __hip_bfloat16 h; unsigned short u; } c;
  c.h = __float2bfloat16(f);
  return c.u;
}
__device__ inline float bf2f(unsigned short u) {
  union { unsigned int i; float f; } c;
  c.i = ((unsigned int)u) << 16;
  return c.f;
}

#define GLL(gp, lp) __builtin_amdgcn_global_load_lds( \
    (const __attribute__((address_space(1))) void*)(gp), \
    (__attribute__((address_space(3))) void*)(lp), 16, 0, 0)

// ---------------- fused fp32 -> bf16 convert for the 4 weight tensors ----------------
__global__ __launch_bounds__(256) void f2bf4_kernel(
    const float* __restrict__ i0, unsigned short* __restrict__ o0, int b0,
    const float* __restrict__ i1, unsigned short* __restrict__ o1, int b1,
    const float* __restrict__ i2, unsigned short* __restrict__ o2, int b2,
    const float* __restrict__ i3, unsigned short* __restrict__ o3)
{
  int blk = blockIdx.x;
  const float* in; unsigned short* out; int base;
  if (blk < b0)           { in = i0; out = o0; base = blk; }
  else if (blk < b0+b1)   { in = i1; out = o1; base = blk - b0; }
  else if (blk < b0+b1+b2){ in = i2; out = o2; base = blk - b0 - b1; }
  else                    { in = i3; out = o3; base = blk - b0 - b1 - b2; }
  int i = (base*256 + threadIdx.x)*4;
  float4 v = *(const float4*)(in + i);
  us4 o;
  o[0] = f2bf(v.x); o[1] = f2bf(v.y); o[2] = f2bf(v.z); o[3] = f2bf(v.w);
  *(us4*)(out + i) = o;
}

// ---------------- RMSNorm: one block per token, bf16 output ----------------
__global__ __launch_bounds__(256) void rmsnorm_kernel(const float* __restrict__ x,
                                                      const float* __restrict__ w,
                                                      unsigned short* __restrict__ xn) {
  int tok = blockIdx.x;
  const float* xr = x + (size_t)tok * D_MODEL;
  unsigned short* xo = xn + (size_t)tok * D_MODEL;
  int t = threadIdx.x;
  float4 v = ((const float4*)xr)[t];
  float ss = v.x*v.x + v.y*v.y + v.z*v.z + v.w*v.w;
  #pragma unroll
  for (int off = 32; off > 0; off >>= 1) ss += __shfl_down(ss, off, 64);
  __shared__ float wsum[4];
  __shared__ float rinv_s;
  int lane = t & 63, wv = t >> 6;
  if (lane == 0) wsum[wv] = ss;
  __syncthreads();
  if (t == 0) {
    float tot = wsum[0] + wsum[1] + wsum[2] + wsum[3];
    rinv_s = 1.0f / sqrtf(tot / (float)D_MODEL + EPS);
  }
  __syncthreads();
  float rinv = rinv_s;
  float4 g = ((const float4*)w)[t];
  us4 o;
  o[0] = f2bf(v.x * rinv * g.x);
  o[1] = f2bf(v.y * rinv * g.y);
  o[2] = f2bf(v.z * rinv * g.z);
  o[3] = f2bf(v.w * rinv * g.w);
  *(us4*)(xo + t*4) = o;
}

// ================== 256x256 8-phase bf16 MFMA GEMM ==================
// Schedule verified in R8 (see R7 notes). Now parameterized:
// lda = row stride of A and W (K dim of the full matrices);
// per-block K chunk = NT*64 at offset blockIdx.z * NT*64 (split-K).
// OBF=1: bf16 out to Cv. OBF=0: fp32 partial to {Cv,P1,P2,P3}[blockIdx.z].
template<int NT, int OBF>
__global__ __launch_bounds__(512) void gemm256_bf16_kernel(
    const unsigned short* __restrict__ A,
    const unsigned short* __restrict__ W,
    void* __restrict__ Cv, int ldc, int lda,
    float* __restrict__ P1, float* __restrict__ P2, float* __restrict__ P3)
{
  __shared__ __align__(16) unsigned short As[2][16384];
  __shared__ __align__(16) unsigned short Bs[2][16384];
  int tid = threadIdx.x;
  int lane = tid & 63;
  int w = tid >> 6;          // 0..7
  int wm = w >> 2, wn = w & 3;
  int bm = blockIdx.x * 256;
  int bn = blockIdx.y * 256;
  int kc = blockIdx.z;
  int koff = kc * (NT*64);
  int r15 = lane & 15, g8 = (lane >> 4) * 8;
  int rbh0 = (w & 3) + (w >> 2) * 8;
  int rbh1 = rbh0 + 4;

  auto stageA = [&](int slot, int tile, int ks, int rb) {
    const unsigned short* src = A + (size_t)(bm + rb*16 + r15) * lda + koff + tile*64 + ks*32 + g8;
    GLL(src, &As[slot][rb*1024 + ks*512]);
  };
  auto stageB = [&](int slot, int tile, int ks, int cb) {
    const unsigned short* src = W + (size_t)(bn + cb*16 + r15) * lda + koff + tile*64 + ks*32 + g8;
    GLL(src, &Bs[slot][cb*1024 + ks*512]);
  };

  stageA(0,0,0,rbh0); stageB(0,0,0,w); stageB(0,0,0,8+w);
  stageA(0,0,0,rbh1);
  stageA(0,0,1,rbh0); stageB(0,0,1,w); stageB(0,0,1,8+w);
  stageA(0,0,1,rbh1);
  stageA(1,1,0,rbh0); stageB(1,1,0,w); stageB(1,1,0,8+w);
  stageA(1,1,0,rbh1);
  stageA(1,1,1,rbh0); stageB(1,1,1,w); stageB(1,1,1,8+w);
  asm volatile("s_waitcnt vmcnt(7)" ::: "memory");
  __builtin_amdgcn_s_barrier();
  __builtin_amdgcn_sched_barrier(0);

  f32x4 acc[8][4] = {};
  short8 bfr[4];

#define PHASE_END()                                                      \
  if (drain) { asm volatile("s_waitcnt vmcnt(0)" ::: "memory"); }        \
  else       { asm volatile("s_waitcnt vmcnt(12)" ::: "memory"); }       \
  __builtin_amdgcn_s_barrier();                                          \
  __builtin_amdgcn_sched_barrier(0);

#define MFMA16(IH)                                                       \
  __builtin_amdgcn_s_setprio(1);                                         \
  _Pragma("unroll")                                                      \
  for (int ii = 0; ii < 4; ++ii) {                                       \
    _Pragma("unroll")                                                    \
    for (int j = 0; j < 4; ++j)                                          \
      acc[(IH)*4+ii][j] = __builtin_amdgcn_mfma_f32_16x16x32_bf16(       \
          af[ii], bfr[j], acc[(IH)*4+ii][j], 0, 0, 0);                   \
  }                                                                      \
  __builtin_amdgcn_s_setprio(0);

#define LOAD_A(KS, IH)                                                   \
  short8 af[4];                                                          \
  _Pragma("unroll")                                                      \
  for (int ii = 0; ii < 4; ++ii)                                         \
    af[ii] = *(const short8*)&As[s][(wm*8 + (IH)*4 + ii)*1024 + (KS)*512 + lane*8];

#define LOAD_B(KS)                                                       \
  _Pragma("unroll")                                                      \
  for (int j = 0; j < 4; ++j)                                            \
    bfr[j] = *(const short8*)&Bs[s][(wn*4 + j)*1024 + (KS)*512 + lane*8];

  for (int t = 0; t < NT; ++t) {
    int s = t & 1;
    const bool drain = (t >= NT-2);
    {
      LOAD_A(0,0)
      LOAD_B(0)
      if (t+1 < NT) { stageA(s^1, t+1, 1, rbh1); }
      MFMA16(0)
      PHASE_END()
    }
    {
      LOAD_A(0,1)
      if (t+2 < NT) { stageA(s, t+2, 0, rbh0); stageB(s, t+2, 0, w); stageB(s, t+2, 0, 8+w); }
      MFMA16(1)
      PHASE_END()
    }
    {
      LOAD_A(1,0)
      LOAD_B(1)
      if (t+2 < NT) { stageA(s, t+2, 0, rbh1); }
      MFMA16(0)
      PHASE_END()
    }
    {
      LOAD_A(1,1)
      if (t+2 < NT) { stageA(s, t+2, 1, rbh0); stageB(s, t+2, 1, w); stageB(s, t+2, 1, 8+w); }
      MFMA16(1)
      PHASE_END()
    }
  }
#undef PHASE_END
#undef MFMA16
#undef LOAD_A
#undef LOAD_B

  float* fout;
  if (OBF == 0) fout = (kc == 0) ? (float*)Cv : (kc == 1) ? P1 : (kc == 2) ? P2 : P3;
  #pragma unroll
  for (int ig = 0; ig < 8; ++ig) {
    #pragma unroll
    for (int j = 0; j < 4; ++j) {
      #pragma unroll
      for (int r = 0; r < 4; ++r) {
        int row = bm + wm*128 + ig*16 + (lane >> 4)*4 + r;
        int col = bn + wn*64 + j*16 + r15;
        if (OBF) ((unsigned short*)Cv)[(size_t)row * ldc + col] = f2bf(acc[ig][j][r]);
        else     fout[(size_t)row * ldc + col] = acc[ig][j][r];
      }
    }
  }
}

// ---------------- out_proj reduce: out = x + p0+p1+p2+p3 (float4) ----------------
__global__ __launch_bounds__(256) void outproj_reduce_kernel(
    const float* __restrict__ p0, const float* __restrict__ p1,
    const float* __restrict__ p2, const float* __restrict__ p3,
    const float* __restrict__ x, float* __restrict__ out)
{
  int i = (blockIdx.x * 256 + threadIdx.x) * 4;
  float4 a = *(const float4*)(p0 + i);
  float4 b = *(const float4*)(p1 + i);
  float4 c = *(const float4*)(p2 + i);
  float4 d = *(const float4*)(p3 + i);
  float4 r = *(const float4*)(x + i);
  float4 o;
  o.x = r.x + a.x + b.x + c.x + d.x;
  o.y = r.y + a.y + b.y + c.y + d.y;
  o.z = r.z + a.z + b.z + c.z + d.z;
  o.w = r.w + a.w + b.w + c.w + d.w;
  *(float4*)(out + i) = o;
}

// ---------------- x_proj bf16 MFMA, split-K — R7-verified single-buffer ----------
__global__ __launch_bounds__(256) void xproj_bf16_kernel(
    const unsigned short* __restrict__ A,   // [NTOK][D_INNER] bf16 (xc)
    const unsigned short* __restrict__ W,   // [96][D_INNER] bf16
    float* __restrict__ Ppart)              // [XKS][NTOK][96]
{
  __shared__ __align__(16) unsigned short Abuf[8*512];
  __shared__ __align__(16) unsigned short Bbuf[6*512];
  int tid = threadIdx.x;
  int lane = tid & 63;
  int w = tid >> 6;
  int bm = blockIdx.x * 128;
  int kc = blockIdx.y;
  const int K = D_INNER;
  int r15 = lane & 15, g = lane >> 4;

  const unsigned short* Ag0 = A + (size_t)(bm + 2*w*16 + r15) * K + g*8 + kc*XKC;
  const unsigned short* Ag1 = Ag0 + (size_t)16 * K;
  const unsigned short* Wg0 = W + (size_t)(w*16 + r15) * K + g*8 + kc*XKC;
  const unsigned short* Wg1 = W + (size_t)((4+w)*16 + r15) * K + g*8 + kc*XKC;
  unsigned short* Al0 = &Abuf[(2*w  )*512];
  unsigned short* Al1 = &Abuf[(2*w+1)*512];
  unsigned short* Bl0 = &Bbuf[w*512];
  unsigned short* Bl1 = &Bbuf[(4+w)*512];

  f32x4 acc[2][6] = {};

  for (int k0 = 0; k0 < XKC; k0 += 32) {
    __syncthreads();
    GLL(Ag0 + k0, Al0);
    GLL(Ag1 + k0, Al1);
    GLL(Wg0 + k0, Bl0);
    if (w < 2) GLL(Wg1 + k0, Bl1);
    __syncthreads();

    short8 af[2], bfr[6];
    #pragma unroll
    for (int i = 0; i < 2; ++i)
      af[i] = *(const short8*)&Abuf[(2*w + i)*512 + lane*8];
    #pragma unroll
    for (int j = 0; j < 6; ++j)
      bfr[j] = *(const short8*)&Bbuf[j*512 + lane*8];
    #pragma unroll
    for (int i = 0; i < 2; ++i)
      #pragma unroll
      for (int j = 0; j < 6; ++j)
        acc[i][j] = __builtin_amdgcn_mfma_f32_16x16x32_bf16(af[i], bfr[j], acc[i][j], 0, 0, 0);
  }

  float* out = Ppart + (size_t)kc * NTOK * 96;
  #pragma unroll
  for (int i = 0; i < 2; ++i) {
    #pragma unroll
    for (int j = 0; j < 6; ++j) {
      #pragma unroll
      for (int r = 0; r < 4; ++r) {
        int row = bm + w*32 + i*16 + (lane >> 4)*4 + r;
        int col = j*16 + (lane & 15);
        out[(size_t)row * 96 + col] = acc[i][j][r];
      }
    }
  }
}

// ---------------- x_proj reduce: sum 8 partials -> dbl fp32 ----------------
__global__ __launch_bounds__(256) void xproj_reduce_kernel(
    const float* __restrict__ Ppart, float* __restrict__ dbl)
{
  int idx = blockIdx.x * 256 + threadIdx.x;   // over NTOK*96
  float s = 0.f;
  #pragma unroll
  for (int k = 0; k < XKS; ++k) s += Ppart[(size_t)k * NTOK * 96 + idx];
  dbl[idx] = s;
}

// ---------------- dt_proj + softplus, VALU v2 (R10-verified) ----------------
__global__ __launch_bounds__(256) void dtproj_kernel(
    const float* __restrict__ dbl,            // [NTOK][96] fp32; dt = cols 0..63
    const unsigned short* __restrict__ Wdt,   // [D_INNER][64] bf16
    const float* __restrict__ bias,           // [D_INNER]
    unsigned short* __restrict__ delta)       // [NTOK][D_INNER] bf16
{
  __shared__ unsigned short Wl[256*68];       // padded stride 68 (34KB)
  __shared__ float dts[16][64];
  int tid = threadIdx.x;
  int dBase = blockIdx.x * 256;
  int tok0 = blockIdx.y * 16;

  #pragma unroll
  for (int i = 0; i < 8; ++i) {
    int idx = i*256 + tid;          // 0..2047 over (row, kc8)
    int row = idx >> 3, kc = (idx & 7) * 8;
    const us4* src = (const us4*)(Wdt + (size_t)(dBase + row)*64 + kc);
    us4 lo = src[0], hi = src[1];
    *(us4*)&Wl[row*68 + kc    ] = lo;
    *(us4*)&Wl[row*68 + kc + 4] = hi;
  }
  {
    int t = tid >> 4, kq = tid & 15;
    *(float4*)&dts[t][kq*4] = *(const float4*)(dbl + (size_t)(tok0 + t)*96 + kq*4);
  }
  __syncthreads();

  int d = dBase + tid;
  float s[16];
  float bd = bias[d];
  #pragma unroll
  for (int t = 0; t < 16; ++t) s[t] = bd;

  #pragma unroll
  for (int j = 0; j < 16; ++j) {      // 4 k per step
    us4 wv = *(const us4*)&Wl[tid*68 + j*4];   // b64, 2-way bank = free
    float w0 = bf2f(wv[0]), w1 = bf2f(wv[1]), w2 = bf2f(wv[2]), w3 = bf2f(wv[3]);
    #pragma unroll
    for (int t = 0; t < 16; ++t) {
      float4 dv = *(const float4*)&dts[t][j*4];  // broadcast
      s[t] = fmaf(dv.x, w0, s[t]);
      s[t] = fmaf(dv.y, w1, s[t]);
      s[t] = fmaf(dv.z, w2, s[t]);
      s[t] = fmaf(dv.w, w3, s[t]);
    }
  }

  #pragma unroll
  for (int t = 0; t < 16; ++t) {
    float v = s[t];
    float sp = (v > 20.f) ? v : __logf(1.f + __expf(v));   // fast stable softplus
    delta[(size_t)(tok0 + t) * D_INNER + d] = f2bf(sp);    // lane-contiguous store
  }
}

// ---------------- depthwise causal conv1d (k=4) + SiLU, all bf16 ----------------
__global__ __launch_bounds__(256) void conv_silu_kernel(
    const unsigned short* __restrict__ xz, const float* __restrict__ cw,
    const float* __restrict__ cb, unsigned short* __restrict__ xcbf)
{
  int idx = blockIdx.x * 256 + threadIdx.x;   // over NTOK*D_INNER/4
  int dq = idx & (D_INNER/4 - 1);
  int tok = idx >> 9;
  int l = tok & (SEQ - 1);
  int d = dq * 4;
  const unsigned short* xi = xz + (size_t)tok * (2*D_INNER) + d;
  us4 v3 = *(const us4*)xi;
  us4 v2 = l >= 1 ? *(const us4*)(xi - 1*(2*D_INNER)) : (us4)0;
  us4 v1 = l >= 2 ? *(const us4*)(xi - 2*(2*D_INNER)) : (us4)0;
  us4 v0 = l >= 3 ? *(const us4*)(xi - 3*(2*D_INNER)) : (us4)0;
  float4 cbv = *(const float4*)(cb + d);
  float cbx[4] = {cbv.x, cbv.y, cbv.z, cbv.w};
  us4 o;
  #pragma unroll
  for (int j = 0; j < 4; ++j) {
    float4 wv = *(const float4*)(cw + (d + j) * 4);
    float s = cbx[j];
    s = fmaf(bf2f(v0[j]), wv.x, s);
    s = fmaf(bf2f(v1[j]), wv.y, s);
    s = fmaf(bf2f(v2[j]), wv.z, s);
    s = fmaf(bf2f(v3[j]), wv.w, s);
    float v = s / (1.f + __expf(-s));
    o[j] = f2bf(v);
  }
  *(us4*)(xcbf + (size_t)tok * D_INNER + d) = o;
}

// ================= chunked selective scan (bf16 inputs) =================
__global__ __launch_bounds__(256) void scan_pass1(
    const unsigned short* __restrict__ delta, const float* __restrict__ dbl,
    const unsigned short* __restrict__ xc, const float* __restrict__ A_log,
    float* __restrict__ P, float* __restrict__ He)
{
  int blk = blockIdx.x;                 // B*CCH*8 blocks
  int d = (blk & 7) * 256 + threadIdx.x;
  int c = (blk >> 3) & (CCH - 1);
  int b = blk >> 8;
  float Adn[16];
  #pragma unroll
  for (int n = 0; n < 16; ++n) Adn[n] = -__expf(A_log[d*16 + n]);
  float h[16] = {};
  float sdl = 0.f;
  int tok0 = b * SEQ + c * TCH;
  for (int t = 0; t < TCH; ++t) {
    size_t tok = (size_t)(tok0 + t);
    float dl = bf2f(delta[tok * D_INNER + d]);
    float xcv = bf2f(xc[tok * D_INNER + d]);
    float u = dl * xcv;
    const float4* bp = (const float4*)(dbl + tok*96 + 64);
    float4 b0 = bp[0], b1 = bp[1], b2 = bp[2], b3 = bp[3];
    float bv[16] = {b0.x,b0.y,b0.z,b0.w, b1.x,b1.y,b1.z,b1.w,
                    b2.x,b2.y,b2.z,b2.w, b3.x,b3.y,b3.z,b3.w};
    sdl += dl;
    #pragma unroll
    for (int n = 0; n < 16; ++n)
      h[n] = fmaf(__expf(dl * Adn[n]), h[n], u * bv[n]);
  }
  size_t base = ((size_t)(b*CCH + c) * 16) * D_INNER + d;
  #pragma unroll
  for (int n = 0; n < 16; ++n) {
    P [base + (size_t)n * D_INNER] = __expf(Adn[n] * sdl);
    He[base + (size_t)n * D_INNER] = h[n];
  }
}

__global__ __launch_bounds__(256) void scan_pass2(
    const float* __restrict__ P, const float* __restrict__ He,
    float* __restrict__ Hin)
{
  int blk = blockIdx.x;                 // B*16*8 = 256 blocks
  int d = (blk & 7) * 256 + threadIdx.x;
  int n = (blk >> 3) & 15;
  int b = blk >> 7;
  float h = 0.f;
  #pragma unroll 4
  for (int c = 0; c < CCH; ++c) {
    size_t idx = ((size_t)(b*CCH + c) * 16 + n) * D_INNER + d;
    Hin[idx] = h;
    h = fmaf(P[idx], h, He[idx]);
  }
}

__global__ __launch_bounds__(256) void scan_pass3(
    const unsigned short* __restrict__ delta, const float* __restrict__ dbl,
    const unsigned short* __restrict__ xc, const unsigned short* __restrict__ xz,
    const float* __restrict__ A_log, const float* __restrict__ Dp,
    const float* __restrict__ Hin, unsigned short* __restrict__ y)
{
  int blk = blockIdx.x;                 // B*CCH*8 blocks
  int d = (blk & 7) * 256 + threadIdx.x;
  int c = (blk >> 3) & (CCH - 1);
  int b = blk >> 8;
  float Adn[16];
  #pragma unroll
  for (int n = 0; n < 16; ++n) Adn[n] = -__expf(A_log[d*16 + n]);
  float Dpd = Dp[d];
  float h[16];
  size_t base = ((size_t)(b*CCH + c) * 16) * D_INNER + d;
  #pragma unroll
  for (int n = 0; n < 16; ++n) h[n] = Hin[base + (size_t)n * D_INNER];
  int tok0 = b * SEQ + c * TCH;
  for (int t = 0; t < TCH; ++t) {
    size_t tok = (size_t)(tok0 + t);
    float dl = bf2f(delta[tok * D_INNER + d]);
    float xcv = bf2f(xc[tok * D_INNER + d]);
    float u = dl * xcv;
    const float4* bp = (const float4*)(dbl + tok*96 + 64);
    float4 b0 = bp[0], b1 = bp[1], b2 = bp[2], b3 = bp[3];
    float4 c0 = bp[4], c1 = bp[5], c2 = bp[6], c3 = bp[7];
    float bv[16] = {b0.x,b0.y,b0.z,b0.w, b1.x,b1.y,b1.z,b1.w,
                    b2.x,b2.y,b2.z,b2.w, b3.x,b3.y,b3.z,b3.w};
    float cv[16] = {c0.x,c0.y,c0.z,c0.w, c1.x,c1.y,c1.z,c1.w,
                    c2.x,c2.y,c2.z,c2.w, c3.x,c3.y,c3.z,c3.w};
    float z = bf2f(xz[tok * (2*D_INNER) + D_INNER + d]);
    float acc = xcv * Dpd;
    #pragma unroll
    for (int n = 0; n < 16; ++n) {
      h[n] = fmaf(__expf(dl * Adn[n]), h[n], u * bv[n]);
      acc = fmaf(h[n], cv[n], acc);
    }
    float sz = z / (1.f + __expf(-z));
    y[tok * D_INNER + d] = f2bf(acc * sz);
  }
}

// ---------------- launch ----------------
extern "C" void kernel_launch(void* const* d_in, const int* in_sizes, int n_in,
                              void* d_out, int out_size, void* d_ws, size_t ws_size,
                              hipStream_t stream) {
  const float* x         = (const float*)d_in[0];
  const float* norm_w    = (const float*)d_in[1];
  const float* in_proj_w = (const float*)d_in[2];
  const float* conv_w    = (const float*)d_in[3];
  const float* conv_b    = (const float*)d_in[4];
  const float* x_proj_w  = (const float*)d_in[5];
  const float* dt_proj_w = (const float*)d_in[6];
  const float* dt_proj_b = (const float*)d_in[7];
  const float* A_log     = (const float*)d_in[8];
  const float* Dp        = (const float*)d_in[9];
  const float* out_proj_w= (const float*)d_in[10];
  float* out = (float*)d_out;

  // Workspace layout (~142 MB). out_proj fp32 partials OVERLAY dead regions:
  //   OP0 @50MB (delta_bf: dead after scan_pass3), OP1 @66MB (xn/w_in: dead after
  //   in_proj), OP2 @89MB (Ppart: dead after xproj_reduce), OP3 @105MB (Pst/Hest:
  //   dead after scan_pass2). out_proj GEMM runs after pass3 — stream-sequential.
  char* ws = (char*)d_ws;
  unsigned short* xz_bf   = (unsigned short*)(ws);                 //   0.. 32 MB
  unsigned short* xc_bf   = (unsigned short*)(ws + ( 32ull<<20));  //  32.. 48 MB
  float*          dbl     = (float*)(ws + ( 48ull<<20));           //  48.. 50 MB
  unsigned short* delta_bf= (unsigned short*)(ws + ( 50ull<<20));  //  50.. 66 MB
  unsigned short* xn_bf   = (unsigned short*)(ws + ( 66ull<<20));  //  66.. 74 MB
  unsigned short* w_in_bf = (unsigned short*)(ws + ( 74ull<<20));  //  74.. 82 MB
  unsigned short* w_out_bf= (unsigned short*)(ws + ( 82ull<<20));  //  82.. 86 MB
  unsigned short* w_xp_bf = (unsigned short*)(ws + ( 86ull<<20));  //  86..86.5 MB
  unsigned short* w_dt_bf = (unsigned short*)(ws + ( 87ull<<20));  //  87..87.5 MB
  float*          Ppart   = (float*)(ws + ( 89ull<<20));           //  89..101.6 MB
  float*          Pst     = (float*)(ws + (102ull<<20));           // 102..110 MB
  float*          Hest    = (float*)(ws + (110ull<<20));           // 110..118 MB
  float*          Hin     = (float*)(ws + (118ull<<20));           // 118..126 MB
  unsigned short* yb_bf   = (unsigned short*)(ws + (126ull<<20));  // 126..142 MB
  float*          OP0     = (float*)(ws + ( 50ull<<20));           // 16 MB overlay
  float*          OP1     = (float*)(ws + ( 66ull<<20));           // 16 MB overlay
  float*          OP2     = (float*)(ws + ( 89ull<<20));           // 16 MB overlay
  float*          OP3     = (float*)(ws + (105ull<<20));           // 16 MB overlay

  // 1. RMSNorm -> bf16
  rmsnorm_kernel<<<NTOK, 256, 0, stream>>>(x, norm_w, xn_bf);

  // 1b. all weight conversions fp32 -> bf16, one launch
  f2bf4_kernel<<<4096+2048+192+128, 256, 0, stream>>>(
      in_proj_w, w_in_bf, 4096,
      out_proj_w, w_out_bf, 2048,
      x_proj_w, w_xp_bf, 192,
      dt_proj_w, w_dt_bf);

  // 2. in_proj (256x256 8-phase bf16 MFMA) -> xz bf16
  {
    dim3 g(NTOK/256, (2*D_INNER)/256, 1);   // (16,16,1)
    gemm256_bf16_kernel<D_MODEL/64, 1><<<g, 512, 0, stream>>>(
        xn_bf, w_in_bf, xz_bf, 2*D_INNER, D_MODEL, nullptr, nullptr, nullptr);
  }

  // 3. depthwise conv + SiLU (bf16 in/out)
  conv_silu_kernel<<<(NTOK*D_INNER/4)/256, 256, 0, stream>>>(xz_bf, conv_w, conv_b, xc_bf);

  // 4. x_proj (bf16 MFMA, split-K=8) + reduce -> dbl fp32
  {
    dim3 g(NTOK/128, XKS);
    xproj_bf16_kernel<<<g, 256, 0, stream>>>(xc_bf, w_xp_bf, Ppart);
    xproj_reduce_kernel<<<(NTOK*96)/256, 256, 0, stream>>>(Ppart, dbl);
  }

  // 5. dt_proj + softplus (VALU v2) -> delta bf16
  {
    dim3 g(D_INNER/256, NTOK/16);   // (8, 256)
    dtproj_kernel<<<g, 256, 0, stream>>>(dbl, w_dt_bf, dt_proj_b, delta_bf);
  }

  // 6. chunked selective scan -> bf16 y
  scan_pass1<<<BATCH*CCH*8, 256, 0, stream>>>(delta_bf, dbl, xc_bf, A_log, Pst, Hest);
  scan_pass2<<<BATCH*16*8, 256, 0, stream>>>(Pst, Hest, Hin);
  scan_pass3<<<BATCH*CCH*8, 256, 0, stream>>>(delta_bf, dbl, xc_bf, xz_bf, A_log, Dp, Hin, yb_bf);

  // 7. out_proj: 256² 8-phase split-K=4 -> fp32 partials, then reduce + residual
  {
    dim3 g(NTOK/256, D_MODEL/256, 4);   // (16,4,4) = 256 blocks
    gemm256_bf16_kernel<(D_INNER/4)/64, 0><<<g, 512, 0, stream>>>(
        yb_bf, w_out_bf, OP0, D_MODEL, D_INNER, OP1, OP2, OP3);
    outproj_reduce_kernel<<<(NTOK*D_MODEL/4)/256, 256, 0, stream>>>(OP0, OP1, OP2, OP3, x, out);
  }
}